// Round 7
// baseline (239.439 us; speedup 1.0000x reference)
//
#include <hip/hip_runtime.h>

// Problem constants (from reference)
constexpr int B = 256, L = 500, D = 3, C = 32, I = 35, H = 512, O = 15, M = 5;
constexpr int KP1 = 48;  // GEMM1 K-dim (I=35) zero-padded to 3 MFMA k-steps (32x32x16)
constexpr int JP = 48;   // Vt row stride (rows 0..34 live; 35..47 never read/written)
constexpr int KPV = 520; // padded K leading dim for Vt
constexpr int G = 100;   // scan chunks
constexpr int LC = 5;    // L / G

typedef __attribute__((ext_vector_type(8))) _Float16 half8;  // MFMA A/B frag
typedef __attribute__((ext_vector_type(2))) _Float16 half2;
typedef __attribute__((ext_vector_type(16))) float f32x16;   // 32x32 C/D frag

// -------------------------------------------------------------------------
// kPrep: all three layout preps, ONE dispatch, ZERO LDS (round-6 had a 50KB
// slab allocated for every block -> 3 blocks/CU; now reg-limited occupancy).
//   role 0 (bx <  L):  xT[l][b][k]  — per-thread row pack + 6x16B stores
//   role 1 (bx < 2L):  Wt[l][h][k]  — coalesced reads, row pack, 6x16B
//   role 2 (else):     Vt[l][j][k]  — wave-per-row register transpose:
//     lane reads V[8*lane+e][j] (stride-O; slab goes L1-hot after row 0),
//     cvt_pkrtz pack, one coalesced 16B store per lane. No zero-fill:
//     rows 35..47 and k>=512 are never read by kB.
// -------------------------------------------------------------------------
__global__ __launch_bounds__(256) void kPrep(const float* __restrict__ inp,
                                             const float* __restrict__ z,
                                             const float* __restrict__ W,
                                             const float* __restrict__ Vmu,
                                             const float* __restrict__ Vsg,
                                             const float* __restrict__ Vpi,
                                             _Float16* __restrict__ xT,
                                             _Float16* __restrict__ Wt,
                                             _Float16* __restrict__ Vt) {
  const int bx = blockIdx.x, tid = threadIdx.x;

  if (bx < L) {
    // ---- role 0: xT ----
    const int l = bx, b = tid;
    float e[36];
    const float* ip = inp + ((size_t)b * L + l) * D;
    e[0] = ip[0]; e[1] = ip[1]; e[2] = ip[2];
    const float4* zp = (const float4*)(z + ((size_t)b * L + l) * C);
#pragma unroll
    for (int q = 0; q < 8; ++q) {
      float4 v = zp[q];
      e[D + 4 * q + 0] = v.x; e[D + 4 * q + 1] = v.y;
      e[D + 4 * q + 2] = v.z; e[D + 4 * q + 3] = v.w;
    }
    e[35] = 0.f;
    unsigned u[24];
#pragma unroll
    for (int q = 0; q < 18; ++q)
      u[q] = __builtin_bit_cast(unsigned, __builtin_amdgcn_cvt_pkrtz(e[2 * q], e[2 * q + 1]));
#pragma unroll
    for (int q = 18; q < 24; ++q) u[q] = 0u;
    uint4* dst = (uint4*)(xT + ((size_t)l * B + b) * KP1);
#pragma unroll
    for (int q = 0; q < 6; ++q) dst[q] = ((const uint4*)u)[q];
  } else if (bx < 2 * L) {
    // ---- role 1: Wt ----
    const int l = bx - L;
#pragma unroll
    for (int hp = 0; hp < 2; ++hp) {
      const int h = tid + 256 * hp;
      float v[36];
#pragma unroll
      for (int i = 0; i < I; ++i) v[i] = W[((size_t)l * I + i) * H + h];  // coalesced
      v[35] = 0.f;
      unsigned u[24];
#pragma unroll
      for (int q = 0; q < 18; ++q)
        u[q] = __builtin_bit_cast(unsigned, __builtin_amdgcn_cvt_pkrtz(v[2 * q], v[2 * q + 1]));
#pragma unroll
      for (int q = 18; q < 24; ++q) u[q] = 0u;
      uint4* dst = (uint4*)(Wt + ((size_t)l * H + h) * KP1);
#pragma unroll
      for (int q = 0; q < 6; ++q) dst[q] = ((const uint4*)u)[q];
    }
  } else {
    // ---- role 2: Vt register transpose, LDS-free ----
    const int l = bx - 2 * L;
    const int w = tid >> 6, lane = tid & 63;
    const int h0 = lane * 8;
    for (int row = w; row < 35; row += 4) {
      const float* src;
      int j, od;
      if (row < O)          { src = Vmu + (size_t)l * H * O; j = row;         od = O; }
      else if (row < 2 * O) { src = Vsg + (size_t)l * H * O; j = row - O;     od = O; }
      else                  { src = Vpi + (size_t)l * H * M; j = row - 2 * O; od = M; }
      float v[8];
#pragma unroll
      for (int e = 0; e < 8; ++e) v[e] = src[(size_t)(h0 + e) * od + j];
      unsigned u[4];
#pragma unroll
      for (int q = 0; q < 4; ++q)
        u[q] = __builtin_bit_cast(unsigned, __builtin_amdgcn_cvt_pkrtz(v[2 * q], v[2 * q + 1]));
      *(uint4*)(Vt + ((size_t)l * JP + row) * KPV + h0) = (uint4){u[0], u[1], u[2], u[3]};
    }
  }
}

// -------------------------------------------------------------------------
// kA: chunk partial sums S_g^T[h][b] = sum_{l in chunk} (x[l] @ W[l])^T, fp16.
// (frozen: t-loop fully unrolled, cross-step load hoisting)
// -------------------------------------------------------------------------
__global__ __launch_bounds__(256, 3) void kA(const _Float16* __restrict__ xT,
                                             const _Float16* __restrict__ Wt,
                                             _Float16* __restrict__ S) {
  const int idx = blockIdx.x;
  const int g = ((idx >> 6) << 3) + (idx & 7);
  if (g >= G) return;
  const int b0 = ((idx >> 3) & 7) * 32;
  const int w = threadIdx.x >> 6, lane = threadIdx.x & 63;
  const int ln31 = lane & 31, hi32 = lane >> 5;

  f32x16 acc[4];
#pragma unroll
  for (int mt = 0; mt < 4; ++mt)
#pragma unroll
    for (int r = 0; r < 16; ++r) acc[mt][r] = 0.f;

#pragma unroll
  for (int t = 0; t < LC; ++t) {
    const int l = g * LC + t;
    const _Float16* Xb = xT + ((size_t)l * B + b0 + ln31) * KP1 + 8 * hi32;
    const _Float16* Wb = Wt + ((size_t)l * H + 128 * w + ln31) * KP1 + 8 * hi32;
    half8 xf[3], wf[12];
#pragma unroll
    for (int kt = 0; kt < 3; ++kt) xf[kt] = *(const half8*)(Xb + 16 * kt);
#pragma unroll
    for (int mt = 0; mt < 4; ++mt)
#pragma unroll
      for (int kt = 0; kt < 3; ++kt)
        wf[mt * 3 + kt] = *(const half8*)(Wb + (size_t)mt * 32 * KP1 + 16 * kt);
#pragma unroll
    for (int mt = 0; mt < 4; ++mt)
#pragma unroll
      for (int kt = 0; kt < 3; ++kt)
        acc[mt] = __builtin_amdgcn_mfma_f32_32x32x16_f16(wf[mt * 3 + kt], xf[kt], acc[mt], 0, 0, 0);
  }
  // store S^T[g][h][b]: D layout col(b)=ln31, row(h)=(r&3)+8*(r>>2)+4*hi32
  _Float16* Sp = S + ((size_t)g * H + 128 * w) * B + b0 + ln31;
#pragma unroll
  for (int mt = 0; mt < 4; ++mt)
#pragma unroll
    for (int r = 0; r < 16; ++r) {
      const int hl = 32 * mt + (r & 3) + 8 * (r >> 2) + 4 * hi32;
      Sp[(size_t)hl * B] = (_Float16)acc[mt][r];
    }
}

// -------------------------------------------------------------------------
// kS: exclusive scan over the G chunk sums per (h,b), + b_enc. Acc fp16.
// -------------------------------------------------------------------------
__global__ __launch_bounds__(256) void kS(const _Float16* __restrict__ S,
                                          const float* __restrict__ benc,
                                          _Float16* __restrict__ Acc) {
  const int t = blockIdx.x * 256 + threadIdx.x;  // B*H threads
  const int b = t & (B - 1), h = t >> 8;
  float run = benc[h];
  const _Float16* sp = S + (size_t)h * B + b;
  _Float16* ap = Acc + (size_t)h * B + b;
  constexpr size_t stride = (size_t)H * B;
#pragma unroll 5
  for (int g = 0; g < G; ++g) {
    ap[g * stride] = (_Float16)run;  // exclusive: write before adding own chunk
    run += (float)sp[g * stride];
  }
}

// -------------------------------------------------------------------------
// kB: fused scan + projection per chunk. (frozen from round 5 — proven)
// Barrier-free l-loop; per-wave fp16 partial slabs; one barrier; fused
// reduce with LDS-staged bias and 700B-contiguous stores.
// -------------------------------------------------------------------------
__global__ __launch_bounds__(256, 2) void kB(const _Float16* __restrict__ xT,
                                             const _Float16* __restrict__ Wt,
                                             const _Float16* __restrict__ Vt,
                                             const _Float16* __restrict__ Acc,
                                             const float* __restrict__ bmu,
                                             const float* __restrict__ bsg,
                                             const float* __restrict__ bpi,
                                             float* __restrict__ out) {
  const int idx = blockIdx.x;
  const int g = ((idx >> 6) << 3) + (idx & 7);
  if (g >= G) return;
  const int b0 = ((idx >> 3) & 7) * 32;
  const int tid = threadIdx.x;
  const int w = tid >> 6, lane = tid & 63;
  const int ln31 = lane & 31, hi32 = lane >> 5;

  __shared__ _Float16 po[4][LC][32][36];  // 46,080 B per-wave partial slabs
  __shared__ float bias_s[LC][35];        // 700 B

  // stage bias once per block (3-way branch runs once, not per step)
  if (tid < LC * 35) {
    const int t = tid / 35, j = tid - 35 * t, l = g * LC + t;
    bias_s[t][j] = (j < O) ? bmu[l * O + j]
                 : (j < 2 * O) ? bsg[l * O + (j - O)]
                 : bpi[l * M + (j - 2 * O)];
  }

  // load running state a = Acc[g] (fp16) into D-layout accumulators
  f32x16 acc[4];
  const _Float16* Ap = Acc + ((size_t)g * H + 128 * w) * B + b0 + ln31;
#pragma unroll
  for (int mt = 0; mt < 4; ++mt)
#pragma unroll
    for (int r = 0; r < 16; ++r) {
      const int hl = 32 * mt + (r & 3) + 8 * (r >> 2) + 4 * hi32;
      acc[mt][r] = (float)Ap[(size_t)hl * B];
    }

#pragma unroll 1
  for (int t = 0; t < LC; ++t) {
    const int l = g * LC + t;
    // ---- issue ALL loads for this step up front ----
    const _Float16* Vb = Vt + (size_t)l * JP * KPV + 128 * w + 8 * hi32;
    half8 va0[8];
#pragma unroll
    for (int s = 0; s < 8; ++s)
      va0[s] = *(const half8*)(Vb + 16 * s + (size_t)ln31 * KPV);
    half8 va1[8];
#pragma unroll
    for (int s = 0; s < 8; ++s) {
      va1[s] = half8{};
      if (ln31 < 3)  // j = 32..34 tail rows
        va1[s] = *(const half8*)(Vb + 16 * s + (size_t)(32 + ln31) * KPV);
    }
    half8 xf[3], wf[12];
    if (t != LC - 1) {
      const _Float16* Xb = xT + ((size_t)l * B + b0 + ln31) * KP1 + 8 * hi32;
      const _Float16* Wb = Wt + ((size_t)l * H + 128 * w + ln31) * KP1 + 8 * hi32;
#pragma unroll
      for (int kt = 0; kt < 3; ++kt) xf[kt] = *(const half8*)(Xb + 16 * kt);
#pragma unroll
      for (int mt = 0; mt < 4; ++mt)
#pragma unroll
        for (int kt = 0; kt < 3; ++kt)
          wf[mt * 3 + kt] = *(const half8*)(Wb + (size_t)mt * 32 * KP1 + 16 * kt);
    }
    // ---- projection: out^T[j][b] += V^T[j][h] * relu(a)[h][b] ----
    f32x16 o0, o1;
#pragma unroll
    for (int r = 0; r < 16; ++r) { o0[r] = 0.f; o1[r] = 0.f; }
#pragma unroll
    for (int mt = 0; mt < 4; ++mt) {
      // relu + pack: P0[m] = halves(rows 8m+4*hi32+{0,1}), P1[m] = {2,3}
      unsigned P0[4], P1[4];
#pragma unroll
      for (int m = 0; m < 4; ++m) {
        float e0 = fmaxf(acc[mt][4 * m + 0], 0.f);
        float e1 = fmaxf(acc[mt][4 * m + 1], 0.f);
        float e2 = fmaxf(acc[mt][4 * m + 2], 0.f);
        float e3 = fmaxf(acc[mt][4 * m + 3], 0.f);
        P0[m] = __builtin_bit_cast(unsigned, __builtin_amdgcn_cvt_pkrtz(e0, e1));
        P1[m] = __builtin_bit_cast(unsigned, __builtin_amdgcn_cvt_pkrtz(e2, e3));
      }
#pragma unroll
      for (int tl = 0; tl < 2; ++tl) {
        // swap vdst.hi <-> vsrc.lo: after swap(X,Y): X=[X.lo|Y.lo], Y=[X.hi|Y.hi]
        unsigned w0 = P0[2 * tl], w2 = P0[2 * tl + 1];
        unsigned w1 = P1[2 * tl], w3 = P1[2 * tl + 1];
        asm("v_permlane32_swap_b32 %0, %1" : "+v"(w0), "+v"(w2));
        asm("v_permlane32_swap_b32 %0, %1" : "+v"(w1), "+v"(w3));
        half2 a0 = __builtin_bit_cast(half2, w0);
        half2 a1 = __builtin_bit_cast(half2, w1);
        half2 a2 = __builtin_bit_cast(half2, w2);
        half2 a3 = __builtin_bit_cast(half2, w3);
        half8 hb = {a0.x, a0.y, a1.x, a1.y, a2.x, a2.y, a3.x, a3.y};
        o0 = __builtin_amdgcn_mfma_f32_32x32x16_f16(va0[2 * mt + tl], hb, o0, 0, 0, 0);
        o1 = __builtin_amdgcn_mfma_f32_32x32x16_f16(va1[2 * mt + tl], hb, o1, 0, 0, 0);
      }
    }
    // ---- per-wave partials to private slab (packed fp16 pairs, no sync) --
    _Float16* pw = &po[w][t][ln31][0];
#pragma unroll
    for (int r = 0; r < 16; r += 2) {
      const int j0 = (r & 3) + 8 * (r >> 2) + 4 * hi32;  // even; pair j0,j0+1
      *(unsigned*)&pw[j0] =
          __builtin_bit_cast(unsigned, __builtin_amdgcn_cvt_pkrtz(o0[r], o0[r + 1]));
    }
    if (hi32 == 0) {  // o1 rows j=32,33,34 live only in hi32==0 lanes
      *(unsigned*)&pw[32] =
          __builtin_bit_cast(unsigned, __builtin_amdgcn_cvt_pkrtz(o1[0], o1[1]));
      pw[34] = (_Float16)o1[2];
    }
    // ---- recurrence: a += (x[l] @ W[l])^T ----
    if (t != LC - 1) {
#pragma unroll
      for (int mt = 0; mt < 4; ++mt)
#pragma unroll
        for (int kt = 0; kt < 3; ++kt)
          acc[mt] = __builtin_amdgcn_mfma_f32_32x32x16_f16(wf[mt * 3 + kt], xf[kt], acc[mt], 0, 0, 0);
    }
  }
  __syncthreads();  // one barrier: po + bias_s visible
  // ---- fused reduce: per b-row 175 contiguous floats (5 l x 35 j) ----
  for (int f = tid; f < 32 * LC * 35; f += 256) {
    const int b = f / (LC * 35);
    const int r = f - b * (LC * 35);
    const int t = r / 35, j = r - 35 * t;
    const float s = (float)po[0][t][b][j] + (float)po[1][t][b][j] +
                    (float)po[2][t][b][j] + (float)po[3][t][b][j];
    out[((size_t)(b0 + b) * L + g * LC + t) * 35 + j] = s + bias_s[t][j];
  }
}

extern "C" void kernel_launch(void* const* d_in, const int* in_sizes, int n_in,
                              void* d_out, int out_size, void* d_ws, size_t ws_size,
                              hipStream_t stream) {
  const float* inp  = (const float*)d_in[0];
  const float* z    = (const float*)d_in[1];
  const float* Wenc = (const float*)d_in[2];
  const float* benc = (const float*)d_in[3];
  const float* Vmu  = (const float*)d_in[4];
  const float* bmu  = (const float*)d_in[5];
  const float* Vsg  = (const float*)d_in[6];
  const float* bsg  = (const float*)d_in[7];
  const float* Vpi  = (const float*)d_in[8];
  const float* bpi  = (const float*)d_in[9];
  float* out = (float*)d_out;

  // Workspace: xT 12.29 + Wt 24.58 + Vt 24.96 + S 26.21 + Acc(fp16) 26.21 = 114.3 MB
  char* ws = (char*)d_ws;
  _Float16* xT  = (_Float16*)ws;                   // [L][B][48]
  _Float16* Wt  = (_Float16*)(ws + 12288000);      // [L][H][48]
  _Float16* Vt  = (_Float16*)(ws + 36864000);      // [L][48][520]
  _Float16* S   = (_Float16*)(ws + 61824000);      // [G][H][B] fp16
  _Float16* Acc = (_Float16*)(ws + 88038400);      // [G][H][B] fp16

  kPrep<<<dim3(3 * L), 256, 0, stream>>>(inp, z, Wenc, Vmu, Vsg, Vpi, xT, Wt, Vt);
  kA<<<dim3(832), 256, 0, stream>>>(xT, Wt, S);
  kS<<<dim3(B * H / 256), 256, 0, stream>>>(S, benc, Acc);
  kB<<<dim3(832), 256, 0, stream>>>(xT, Wt, Vt, Acc, bmu, bsg, bpi, out);
}

// Round 8
// 236.048 us; speedup vs baseline: 1.0144x; 1.0144x over previous
//
#include <hip/hip_runtime.h>

// Problem constants (from reference)
constexpr int B = 256, L = 500, D = 3, C = 32, I = 35, H = 512, O = 15, M = 5;
constexpr int KP1 = 48;  // GEMM1 K-dim (I=35) zero-padded to 3 MFMA k-steps (32x32x16)
constexpr int JP = 48;   // Vt row stride (rows 0..34 live; 35..47 never read/written)
constexpr int KPV = 520; // padded K leading dim for Vt
constexpr int G = 100;   // scan chunks
constexpr int LC = 5;    // L / G

typedef __attribute__((ext_vector_type(8))) _Float16 half8;  // MFMA A/B frag
typedef __attribute__((ext_vector_type(2))) _Float16 half2;
typedef __attribute__((ext_vector_type(16))) float f32x16;   // 32x32 C/D frag

// -------------------------------------------------------------------------
// kPrep: all three layout preps, ONE dispatch, zero LDS.
// Round-8: __launch_bounds__(256,2) — round 7 compiled to VGPR=32, which
// serializes the load streams (few loads in flight -> 1.8 TB/s cap).
// Relaxing the reg cap lets all per-thread loads issue before the packs.
// Grid 2000: role1 split into (l, hp) single-pass blocks for balance.
//   role 0 (bx <  L):        xT[l][b][k]
//   role 1 (L <= bx < 3L):   Wt[l][h][k], one 256-h pass per block
//   role 2 (bx >= 3L):       Vt[l][j][k] wave-per-row register transpose
// -------------------------------------------------------------------------
__global__ __launch_bounds__(256, 2) void kPrep(const float* __restrict__ inp,
                                                const float* __restrict__ z,
                                                const float* __restrict__ W,
                                                const float* __restrict__ Vmu,
                                                const float* __restrict__ Vsg,
                                                const float* __restrict__ Vpi,
                                                _Float16* __restrict__ xT,
                                                _Float16* __restrict__ Wt,
                                                _Float16* __restrict__ Vt) {
  const int bx = blockIdx.x, tid = threadIdx.x;

  if (bx < L) {
    // ---- role 0: xT ----
    const int l = bx, b = tid;
    float e[36];
    const float* ip = inp + ((size_t)b * L + l) * D;
    e[0] = ip[0]; e[1] = ip[1]; e[2] = ip[2];
    const float4* zp = (const float4*)(z + ((size_t)b * L + l) * C);
#pragma unroll
    for (int q = 0; q < 8; ++q) {
      float4 v = zp[q];
      e[D + 4 * q + 0] = v.x; e[D + 4 * q + 1] = v.y;
      e[D + 4 * q + 2] = v.z; e[D + 4 * q + 3] = v.w;
    }
    e[35] = 0.f;
    unsigned u[24];
#pragma unroll
    for (int q = 0; q < 18; ++q)
      u[q] = __builtin_bit_cast(unsigned, __builtin_amdgcn_cvt_pkrtz(e[2 * q], e[2 * q + 1]));
#pragma unroll
    for (int q = 18; q < 24; ++q) u[q] = 0u;
    uint4* dst = (uint4*)(xT + ((size_t)l * B + b) * KP1);
#pragma unroll
    for (int q = 0; q < 6; ++q) dst[q] = ((const uint4*)u)[q];
  } else if (bx < 3 * L) {
    // ---- role 1: Wt, one h-pass per block ----
    const int t = bx - L;
    const int l = t >> 1, hp = t & 1;
    const int h = tid + 256 * hp;
    float v[36];
#pragma unroll
    for (int i = 0; i < I; ++i) v[i] = W[((size_t)l * I + i) * H + h];  // coalesced
    v[35] = 0.f;
    unsigned u[24];
#pragma unroll
    for (int q = 0; q < 18; ++q)
      u[q] = __builtin_bit_cast(unsigned, __builtin_amdgcn_cvt_pkrtz(v[2 * q], v[2 * q + 1]));
#pragma unroll
    for (int q = 18; q < 24; ++q) u[q] = 0u;
    uint4* dst = (uint4*)(Wt + ((size_t)l * H + h) * KP1);
#pragma unroll
    for (int q = 0; q < 6; ++q) dst[q] = ((const uint4*)u)[q];
  } else {
    // ---- role 2: Vt register transpose, LDS-free ----
    const int l = bx - 3 * L;
    const int w = tid >> 6, lane = tid & 63;
    const int h0 = lane * 8;
    for (int row = w; row < 35; row += 4) {
      const float* src;
      int j, od;
      if (row < O)          { src = Vmu + (size_t)l * H * O; j = row;         od = O; }
      else if (row < 2 * O) { src = Vsg + (size_t)l * H * O; j = row - O;     od = O; }
      else                  { src = Vpi + (size_t)l * H * M; j = row - 2 * O; od = M; }
      float v[8];
#pragma unroll
      for (int e = 0; e < 8; ++e) v[e] = src[(size_t)(h0 + e) * od + j];
      unsigned u[4];
#pragma unroll
      for (int q = 0; q < 4; ++q)
        u[q] = __builtin_bit_cast(unsigned, __builtin_amdgcn_cvt_pkrtz(v[2 * q], v[2 * q + 1]));
      *(uint4*)(Vt + ((size_t)l * JP + row) * KPV + h0) = (uint4){u[0], u[1], u[2], u[3]};
    }
  }
}

// -------------------------------------------------------------------------
// kA: chunk partial sums S_g^T[h][b] = sum_{l in chunk} (x[l] @ W[l])^T, fp16.
// (frozen: t-loop fully unrolled, cross-step load hoisting)
// -------------------------------------------------------------------------
__global__ __launch_bounds__(256, 3) void kA(const _Float16* __restrict__ xT,
                                             const _Float16* __restrict__ Wt,
                                             _Float16* __restrict__ S) {
  const int idx = blockIdx.x;
  const int g = ((idx >> 6) << 3) + (idx & 7);
  if (g >= G) return;
  const int b0 = ((idx >> 3) & 7) * 32;
  const int w = threadIdx.x >> 6, lane = threadIdx.x & 63;
  const int ln31 = lane & 31, hi32 = lane >> 5;

  f32x16 acc[4];
#pragma unroll
  for (int mt = 0; mt < 4; ++mt)
#pragma unroll
    for (int r = 0; r < 16; ++r) acc[mt][r] = 0.f;

#pragma unroll
  for (int t = 0; t < LC; ++t) {
    const int l = g * LC + t;
    const _Float16* Xb = xT + ((size_t)l * B + b0 + ln31) * KP1 + 8 * hi32;
    const _Float16* Wb = Wt + ((size_t)l * H + 128 * w + ln31) * KP1 + 8 * hi32;
    half8 xf[3], wf[12];
#pragma unroll
    for (int kt = 0; kt < 3; ++kt) xf[kt] = *(const half8*)(Xb + 16 * kt);
#pragma unroll
    for (int mt = 0; mt < 4; ++mt)
#pragma unroll
      for (int kt = 0; kt < 3; ++kt)
        wf[mt * 3 + kt] = *(const half8*)(Wb + (size_t)mt * 32 * KP1 + 16 * kt);
#pragma unroll
    for (int mt = 0; mt < 4; ++mt)
#pragma unroll
      for (int kt = 0; kt < 3; ++kt)
        acc[mt] = __builtin_amdgcn_mfma_f32_32x32x16_f16(wf[mt * 3 + kt], xf[kt], acc[mt], 0, 0, 0);
  }
  // store S^T[g][h][b]: D layout col(b)=ln31, row(h)=(r&3)+8*(r>>2)+4*hi32
  _Float16* Sp = S + ((size_t)g * H + 128 * w) * B + b0 + ln31;
#pragma unroll
  for (int mt = 0; mt < 4; ++mt)
#pragma unroll
    for (int r = 0; r < 16; ++r) {
      const int hl = 32 * mt + (r & 3) + 8 * (r >> 2) + 4 * hi32;
      Sp[(size_t)hl * B] = (_Float16)acc[mt][r];
    }
}

// -------------------------------------------------------------------------
// kS: exclusive scan over the G chunk sums per (h,b), + b_enc. Acc fp16.
// -------------------------------------------------------------------------
__global__ __launch_bounds__(256) void kS(const _Float16* __restrict__ S,
                                          const float* __restrict__ benc,
                                          _Float16* __restrict__ Acc) {
  const int t = blockIdx.x * 256 + threadIdx.x;  // B*H threads
  const int b = t & (B - 1), h = t >> 8;
  float run = benc[h];
  const _Float16* sp = S + (size_t)h * B + b;
  _Float16* ap = Acc + (size_t)h * B + b;
  constexpr size_t stride = (size_t)H * B;
#pragma unroll 5
  for (int g = 0; g < G; ++g) {
    ap[g * stride] = (_Float16)run;  // exclusive: write before adding own chunk
    run += (float)sp[g * stride];
  }
}

// -------------------------------------------------------------------------
// kB: fused scan + projection per chunk. (frozen from round 5 — proven)
// Barrier-free l-loop; per-wave fp16 partial slabs; one barrier; fused
// reduce with LDS-staged bias and 700B-contiguous stores.
// -------------------------------------------------------------------------
__global__ __launch_bounds__(256, 2) void kB(const _Float16* __restrict__ xT,
                                             const _Float16* __restrict__ Wt,
                                             const _Float16* __restrict__ Vt,
                                             const _Float16* __restrict__ Acc,
                                             const float* __restrict__ bmu,
                                             const float* __restrict__ bsg,
                                             const float* __restrict__ bpi,
                                             float* __restrict__ out) {
  const int idx = blockIdx.x;
  const int g = ((idx >> 6) << 3) + (idx & 7);
  if (g >= G) return;
  const int b0 = ((idx >> 3) & 7) * 32;
  const int tid = threadIdx.x;
  const int w = tid >> 6, lane = tid & 63;
  const int ln31 = lane & 31, hi32 = lane >> 5;

  __shared__ _Float16 po[4][LC][32][36];  // 46,080 B per-wave partial slabs
  __shared__ float bias_s[LC][35];        // 700 B

  // stage bias once per block (3-way branch runs once, not per step)
  if (tid < LC * 35) {
    const int t = tid / 35, j = tid - 35 * t, l = g * LC + t;
    bias_s[t][j] = (j < O) ? bmu[l * O + j]
                 : (j < 2 * O) ? bsg[l * O + (j - O)]
                 : bpi[l * M + (j - 2 * O)];
  }

  // load running state a = Acc[g] (fp16) into D-layout accumulators
  f32x16 acc[4];
  const _Float16* Ap = Acc + ((size_t)g * H + 128 * w) * B + b0 + ln31;
#pragma unroll
  for (int mt = 0; mt < 4; ++mt)
#pragma unroll
    for (int r = 0; r < 16; ++r) {
      const int hl = 32 * mt + (r & 3) + 8 * (r >> 2) + 4 * hi32;
      acc[mt][r] = (float)Ap[(size_t)hl * B];
    }

#pragma unroll 1
  for (int t = 0; t < LC; ++t) {
    const int l = g * LC + t;
    // ---- issue ALL loads for this step up front ----
    const _Float16* Vb = Vt + (size_t)l * JP * KPV + 128 * w + 8 * hi32;
    half8 va0[8];
#pragma unroll
    for (int s = 0; s < 8; ++s)
      va0[s] = *(const half8*)(Vb + 16 * s + (size_t)ln31 * KPV);
    half8 va1[8];
#pragma unroll
    for (int s = 0; s < 8; ++s) {
      va1[s] = half8{};
      if (ln31 < 3)  // j = 32..34 tail rows
        va1[s] = *(const half8*)(Vb + 16 * s + (size_t)(32 + ln31) * KPV);
    }
    half8 xf[3], wf[12];
    if (t != LC - 1) {
      const _Float16* Xb = xT + ((size_t)l * B + b0 + ln31) * KP1 + 8 * hi32;
      const _Float16* Wb = Wt + ((size_t)l * H + 128 * w + ln31) * KP1 + 8 * hi32;
#pragma unroll
      for (int kt = 0; kt < 3; ++kt) xf[kt] = *(const half8*)(Xb + 16 * kt);
#pragma unroll
      for (int mt = 0; mt < 4; ++mt)
#pragma unroll
        for (int kt = 0; kt < 3; ++kt)
          wf[mt * 3 + kt] = *(const half8*)(Wb + (size_t)mt * 32 * KP1 + 16 * kt);
    }
    // ---- projection: out^T[j][b] += V^T[j][h] * relu(a)[h][b] ----
    f32x16 o0, o1;
#pragma unroll
    for (int r = 0; r < 16; ++r) { o0[r] = 0.f; o1[r] = 0.f; }
#pragma unroll
    for (int mt = 0; mt < 4; ++mt) {
      // relu + pack: P0[m] = halves(rows 8m+4*hi32+{0,1}), P1[m] = {2,3}
      unsigned P0[4], P1[4];
#pragma unroll
      for (int m = 0; m < 4; ++m) {
        float e0 = fmaxf(acc[mt][4 * m + 0], 0.f);
        float e1 = fmaxf(acc[mt][4 * m + 1], 0.f);
        float e2 = fmaxf(acc[mt][4 * m + 2], 0.f);
        float e3 = fmaxf(acc[mt][4 * m + 3], 0.f);
        P0[m] = __builtin_bit_cast(unsigned, __builtin_amdgcn_cvt_pkrtz(e0, e1));
        P1[m] = __builtin_bit_cast(unsigned, __builtin_amdgcn_cvt_pkrtz(e2, e3));
      }
#pragma unroll
      for (int tl = 0; tl < 2; ++tl) {
        // swap vdst.hi <-> vsrc.lo: after swap(X,Y): X=[X.lo|Y.lo], Y=[X.hi|Y.hi]
        unsigned w0 = P0[2 * tl], w2 = P0[2 * tl + 1];
        unsigned w1 = P1[2 * tl], w3 = P1[2 * tl + 1];
        asm("v_permlane32_swap_b32 %0, %1" : "+v"(w0), "+v"(w2));
        asm("v_permlane32_swap_b32 %0, %1" : "+v"(w1), "+v"(w3));
        half2 a0 = __builtin_bit_cast(half2, w0);
        half2 a1 = __builtin_bit_cast(half2, w1);
        half2 a2 = __builtin_bit_cast(half2, w2);
        half2 a3 = __builtin_bit_cast(half2, w3);
        half8 hb = {a0.x, a0.y, a1.x, a1.y, a2.x, a2.y, a3.x, a3.y};
        o0 = __builtin_amdgcn_mfma_f32_32x32x16_f16(va0[2 * mt + tl], hb, o0, 0, 0, 0);
        o1 = __builtin_amdgcn_mfma_f32_32x32x16_f16(va1[2 * mt + tl], hb, o1, 0, 0, 0);
      }
    }
    // ---- per-wave partials to private slab (packed fp16 pairs, no sync) --
    _Float16* pw = &po[w][t][ln31][0];
#pragma unroll
    for (int r = 0; r < 16; r += 2) {
      const int j0 = (r & 3) + 8 * (r >> 2) + 4 * hi32;  // even; pair j0,j0+1
      *(unsigned*)&pw[j0] =
          __builtin_bit_cast(unsigned, __builtin_amdgcn_cvt_pkrtz(o0[r], o0[r + 1]));
    }
    if (hi32 == 0) {  // o1 rows j=32,33,34 live only in hi32==0 lanes
      *(unsigned*)&pw[32] =
          __builtin_bit_cast(unsigned, __builtin_amdgcn_cvt_pkrtz(o1[0], o1[1]));
      pw[34] = (_Float16)o1[2];
    }
    // ---- recurrence: a += (x[l] @ W[l])^T ----
    if (t != LC - 1) {
#pragma unroll
      for (int mt = 0; mt < 4; ++mt)
#pragma unroll
        for (int kt = 0; kt < 3; ++kt)
          acc[mt] = __builtin_amdgcn_mfma_f32_32x32x16_f16(wf[mt * 3 + kt], xf[kt], acc[mt], 0, 0, 0);
    }
  }
  __syncthreads();  // one barrier: po + bias_s visible
  // ---- fused reduce: per b-row 175 contiguous floats (5 l x 35 j) ----
  for (int f = tid; f < 32 * LC * 35; f += 256) {
    const int b = f / (LC * 35);
    const int r = f - b * (LC * 35);
    const int t = r / 35, j = r - 35 * t;
    const float s = (float)po[0][t][b][j] + (float)po[1][t][b][j] +
                    (float)po[2][t][b][j] + (float)po[3][t][b][j];
    out[((size_t)(b0 + b) * L + g * LC + t) * 35 + j] = s + bias_s[t][j];
  }
}

extern "C" void kernel_launch(void* const* d_in, const int* in_sizes, int n_in,
                              void* d_out, int out_size, void* d_ws, size_t ws_size,
                              hipStream_t stream) {
  const float* inp  = (const float*)d_in[0];
  const float* z    = (const float*)d_in[1];
  const float* Wenc = (const float*)d_in[2];
  const float* benc = (const float*)d_in[3];
  const float* Vmu  = (const float*)d_in[4];
  const float* bmu  = (const float*)d_in[5];
  const float* Vsg  = (const float*)d_in[6];
  const float* bsg  = (const float*)d_in[7];
  const float* Vpi  = (const float*)d_in[8];
  const float* bpi  = (const float*)d_in[9];
  float* out = (float*)d_out;

  // Workspace: xT 12.29 + Wt 24.58 + Vt 24.96 + S 26.21 + Acc(fp16) 26.21 = 114.3 MB
  char* ws = (char*)d_ws;
  _Float16* xT  = (_Float16*)ws;                   // [L][B][48]
  _Float16* Wt  = (_Float16*)(ws + 12288000);      // [L][H][48]
  _Float16* Vt  = (_Float16*)(ws + 36864000);      // [L][48][520]
  _Float16* S   = (_Float16*)(ws + 61824000);      // [G][H][B] fp16
  _Float16* Acc = (_Float16*)(ws + 88038400);      // [G][H][B] fp16

  kPrep<<<dim3(4 * L), 256, 0, stream>>>(inp, z, Wenc, Vmu, Vsg, Vpi, xT, Wt, Vt);
  kA<<<dim3(832), 256, 0, stream>>>(xT, Wt, S);
  kS<<<dim3(B * H / 256), 256, 0, stream>>>(S, benc, Acc);
  kB<<<dim3(832), 256, 0, stream>>>(xT, Wt, Vt, Acc, bmu, bsg, bpi, out);
}